// Round 9
// baseline (108.115 us; speedup 1.0000x reference)
//
#include <hip/hip_runtime.h>

// Problem: B=4096, D=2, H=2048.
// e = sum_d enc[b,d,h]; d = sum_d dec[b,d,h]; S = e @ d^T (4096x4096)
// M = S on diag, -S off diag; LL = log_sigmoid(M)
// logLoss = -(sum(LL) + 39*sum(diag LL))/B ; diagonalLoss = -40*sum(diag LL)/B
//
// This version: GEMM in MX-scaled FP8 (e4m3, scales=1.0). e,d pre-scaled by 32
// (sigma ~0.9 in e4m3 sweet spot); S descaled by 1/1024 in epilogue.

#define BDIM 4096
#define HDIM 2048
#define BM 256
#define BN 256
#define BK 128
#define NT (HDIM / BK)               // 16 K-tiles
#define NBLK ((BDIM/BM) * (BDIM/BN)) // 256 blocks

typedef __attribute__((ext_vector_type(4))) int   i32x4;
typedef __attribute__((ext_vector_type(8))) int   i32x8;
typedef __attribute__((ext_vector_type(4))) float f32x4;

__device__ __forceinline__ void gll16(const void* g, void* l) {
    __builtin_amdgcn_global_load_lds(
        (const __attribute__((address_space(1))) unsigned int*)g,
        (__attribute__((address_space(3))) unsigned int*)l,
        16, 0, 0);
}

__device__ __forceinline__ i32x8 mk8(i32x4 lo, i32x4 hi) {
    i32x8 r;
    r[0] = lo[0]; r[1] = lo[1]; r[2] = lo[2]; r[3] = lo[3];
    r[4] = hi[0]; r[5] = hi[1]; r[6] = hi[2]; r[7] = hi[3];
    return r;
}

// ---------------- Kernel 1: D-reduce + scale + cast to fp8 e4m3 ----------------
// enc [4096][2][2048] f32 -> eb [4096][2048] fp8 of 32*(l0+l1). 1M threads, 8 elems each.
__global__ void reduce_cast(const float4* __restrict__ enc,
                            const float4* __restrict__ dec,
                            uint2* __restrict__ eb8,
                            uint2* __restrict__ db8) {
    int idx = blockIdx.x * blockDim.x + threadIdx.x;   // 0..1048575
    int b  = idx >> 8;
    int ch = idx & 255;
    int f4 = b * 1024 + ch * 2;

    {
        float4 a0 = enc[f4],       a1 = enc[f4 + 1];
        float4 c0 = enc[f4 + 512], c1 = enc[f4 + 512 + 1];
        int w0 = __builtin_amdgcn_cvt_pk_fp8_f32((a0.x + c0.x) * 32.f, (a0.y + c0.y) * 32.f, 0, false);
        w0     = __builtin_amdgcn_cvt_pk_fp8_f32((a0.z + c0.z) * 32.f, (a0.w + c0.w) * 32.f, w0, true);
        int w1 = __builtin_amdgcn_cvt_pk_fp8_f32((a1.x + c1.x) * 32.f, (a1.y + c1.y) * 32.f, 0, false);
        w1     = __builtin_amdgcn_cvt_pk_fp8_f32((a1.z + c1.z) * 32.f, (a1.w + c1.w) * 32.f, w1, true);
        eb8[idx] = make_uint2((unsigned int)w0, (unsigned int)w1);
    }
    {
        float4 a0 = dec[f4],       a1 = dec[f4 + 1];
        float4 c0 = dec[f4 + 512], c1 = dec[f4 + 512 + 1];
        int w0 = __builtin_amdgcn_cvt_pk_fp8_f32((a0.x + c0.x) * 32.f, (a0.y + c0.y) * 32.f, 0, false);
        w0     = __builtin_amdgcn_cvt_pk_fp8_f32((a0.z + c0.z) * 32.f, (a0.w + c0.w) * 32.f, w0, true);
        int w1 = __builtin_amdgcn_cvt_pk_fp8_f32((a1.x + c1.x) * 32.f, (a1.y + c1.y) * 32.f, 0, false);
        w1     = __builtin_amdgcn_cvt_pk_fp8_f32((a1.z + c1.z) * 32.f, (a1.w + c1.w) * 32.f, w1, true);
        db8[idx] = make_uint2((unsigned int)w0, (unsigned int)w1);
    }
}

// ------------- Kernel 2: MX-fp8 256x256 GEMM (K-tile 128) + fused log-sigmoid -------------
// 8 waves (2M x 4N), per-wave 128x64 output, acc[8][4] f32x4, mfma_scale 16x16x128 fp8.
// LDS 128 KiB: 2 bufs x (A[256][128] + B[256][128]) fp8. Fence-light loop (R8-proven):
// per tile {8 gll stage(t+1 -> buf^1); 24 ds_read_b128 + 32 MFMA unfenced;
// lgkmcnt(0)+vmcnt(0); s_barrier}. Rows are 128 B (bank-wrap), so 16B-slot XOR
// swizzle ^(row&7) on read; global source col inverse-XOR'd, gll dest linear.
__global__ __launch_bounds__(512, 2) void gemm_reduce(
        const unsigned char* __restrict__ eb,
        const unsigned char* __restrict__ db,
        float* __restrict__ pall,
        float* __restrict__ pdiag) {
    __shared__ __align__(16) unsigned char lds8[131072];  // buf*65536: A 0..32767, B 32768..65535

    const int tid  = threadIdx.x;
    const int lane = tid & 63;
    const int wid  = tid >> 6;          // 0..7
    const int wr   = wid >> 2;          // 0..1  (M)
    const int wc   = wid & 3;           // 0..3  (N)
    const int bm   = blockIdx.y, bn = blockIdx.x;
    const int row0 = bm * BM, col0 = bn * BN;

    const int fr = lane & 15;           // fragment row/col
    const int kg = lane >> 4;           // 32B k-granule (0..3) within K=128
    const int s0 = (2 * kg)     ^ (fr & 7);   // swizzled 16B slot, low half
    const int s1 = (2 * kg + 1) ^ (fr & 7);   // swizzled 16B slot, high half

    // staging: thread t covers (row = c*64 + t>>3, slot = t&7) of a 64-row chunk;
    // source col inverse-XOR'd so linear LDS dest + XOR read = identity.
    const int su = tid >> 3;                              // 0..63
    const int sx = ((tid & 7) ^ (su & 7)) << 4;           // source byte offset in row

    f32x4 acc[8][4] = {};

#define ST_A(tp) { const int kt = (tp) * BK; unsigned char* d = &lds8[((tp) & 1) * 65536]; \
    _Pragma("unroll") for (int c = 0; c < 4; ++c) \
        gll16(eb + (size_t)(row0 + c * 64 + su) * HDIM + kt + sx, d + c * 8192 + tid * 16); }
#define ST_B(tp) { const int kt = (tp) * BK; unsigned char* d = &lds8[((tp) & 1) * 65536 + 32768]; \
    _Pragma("unroll") for (int c = 0; c < 4; ++c) \
        gll16(db + (size_t)(col0 + c * 64 + su) * HDIM + kt + sx, d + c * 8192 + tid * 16); }

#define RD16(base, r, sl) (*(const i32x4*)&lds8[(base) + (r) * 128 + ((sl) << 4)])

    // one K-tile (K=128): stage next, read 4 B-frags + 8 A-frags, 32 MFMA, gate+barrier
#define TILE(tau, buf) {                                                         \
    if ((tau) + 1 < NT) { ST_A((tau) + 1) ST_B((tau) + 1) }                      \
    const int ab = (buf) * 65536, bb = ab + 32768;                               \
    i32x8 bfr[4];                                                                \
    _Pragma("unroll") for (int n = 0; n < 4; ++n) {                              \
        const int rB = wc * 64 + n * 16 + fr;                                    \
        bfr[n] = mk8(RD16(bb, rB, s0), RD16(bb, rB, s1));                        \
    }                                                                            \
    _Pragma("unroll") for (int m = 0; m < 8; ++m) {                              \
        const int rA = wr * 128 + m * 16 + fr;                                   \
        i32x8 af = mk8(RD16(ab, rA, s0), RD16(ab, rA, s1));                      \
        _Pragma("unroll") for (int n = 0; n < 4; ++n)                            \
            acc[m][n] = __builtin_amdgcn_mfma_scale_f32_16x16x128_f8f6f4(        \
                af, bfr[n], acc[m][n], 0, 0,                                     \
                0, 0x7F7F7F7F, 0, 0x7F7F7F7F);                                   \
    }                                                                            \
    asm volatile("s_waitcnt lgkmcnt(0) vmcnt(0)" ::: "memory");                  \
    __builtin_amdgcn_s_barrier(); }

    // prologue: tile 0 -> buf0
    ST_A(0) ST_B(0)
    asm volatile("s_waitcnt vmcnt(0)" ::: "memory");
    __builtin_amdgcn_s_barrier();

    for (int tt = 0; tt < NT; tt += 2) {
        TILE(tt, 0)
        TILE(tt + 1, 1)
    }
#undef TILE
#undef RD16
#undef ST_A
#undef ST_B

    // ---- epilogue: descale + log-sigmoid + reduce ----
    // C/D layout: col = lane&15, row = (lane>>4)*4 + reg (shape-determined, m128)
    const int rbase = row0 + wr * 128 + (kg * 4);
    const int cbase = col0 + wc * 64 + fr;
    float s_all = 0.f, s_diag = 0.f;
#pragma unroll
    for (int m = 0; m < 8; ++m) {
#pragma unroll
        for (int n = 0; n < 4; ++n) {
#pragma unroll
            for (int r = 0; r < 4; ++r) {
                float xs = acc[m][n][r] * 0.0009765625f;   // /1024 descale (32*32)
                int row = rbase + m * 16 + r;
                int col = cbase + n * 16;
                bool dg = (row == col);
                float x = dg ? xs : -xs;
                float ll = fminf(x, 0.f) - __logf(1.f + __expf(-fabsf(x)));
                s_all += ll;
                if (dg) s_diag += ll;
            }
        }
    }

#pragma unroll
    for (int off = 32; off; off >>= 1) {
        s_all  += __shfl_down(s_all, off);
        s_diag += __shfl_down(s_diag, off);
    }
    __syncthreads();                    // resync before LDS reuse
    float* red = (float*)lds8;
    if (lane == 0) { red[wid] = s_all; red[8 + wid] = s_diag; }
    __syncthreads();
    if (tid == 0) {
        float A = 0.f, D = 0.f;
#pragma unroll
        for (int w = 0; w < 8; ++w) { A += red[w]; D += red[8 + w]; }
        int bflat = bm * gridDim.x + bn;
        pall[bflat]  = A;
        pdiag[bflat] = D;
    }
}

// ---------------- Kernel 3: finalize ----------------
__global__ void finalize(const float* __restrict__ pall,
                         const float* __restrict__ pdiag,
                         float* __restrict__ out) {
    float a = 0.f, d = 0.f;
    for (int i = threadIdx.x; i < NBLK; i += 256) { a += pall[i]; d += pdiag[i]; }
#pragma unroll
    for (int off = 32; off; off >>= 1) {
        a += __shfl_down(a, off);
        d += __shfl_down(d, off);
    }
    __shared__ float r[8];
    int wid = threadIdx.x >> 6, lane = threadIdx.x & 63;
    if (lane == 0) { r[wid] = a; r[4 + wid] = d; }
    __syncthreads();
    if (threadIdx.x == 0) {
        float A = r[0] + r[1] + r[2] + r[3];
        float D = r[4] + r[5] + r[6] + r[7];
        out[0] = -(A + 39.f * D) / (float)BDIM;  // logLoss
        out[1] = -(40.f * D) / (float)BDIM;      // diagonalLoss
    }
}

extern "C" void kernel_launch(void* const* d_in, const int* in_sizes, int n_in,
                              void* d_out, int out_size, void* d_ws, size_t ws_size,
                              hipStream_t stream) {
    const float* enc = (const float*)d_in[0];
    const float* dec = (const float*)d_in[1];
    float* out = (float*)d_out;

    char* ws = (char*)d_ws;
    // ws: eb 8MB | db 8MB | pall 1KB | pdiag 1KB
    unsigned char* eb = (unsigned char*)ws;
    unsigned char* db = (unsigned char*)(ws + (size_t)8 * 1024 * 1024);
    float* pall  = (float*)(ws + (size_t)16 * 1024 * 1024);
    float* pdiag = pall + NBLK;

    reduce_cast<<<4096, 256, 0, stream>>>(
        (const float4*)enc, (const float4*)dec, (uint2*)eb, (uint2*)db);

    dim3 grid(BDIM / BN, BDIM / BM);  // (16, 16) = 256 blocks = 1/CU
    gemm_reduce<<<grid, 512, 0, stream>>>(eb, db, pall, pdiag);

    finalize<<<1, 256, 0, stream>>>(pall, pdiag, out);
}

// Round 10
// 67.700 us; speedup vs baseline: 1.5970x; 1.5970x over previous
//
#include <hip/hip_runtime.h>

// Problem: B=4096, D=2, H=2048.
// e = sum_d enc[b,d,h]; d = sum_d dec[b,d,h]; S = e @ d^T (4096x4096)
// M = S on diag, -S off diag; LL = log_sigmoid(M)
// logLoss = -(sum(LL) + 39*sum(diag LL))/B ; diagonalLoss = -40*sum(diag LL)/B
//
// GEMM in MX-scaled FP8 (e4m3, scales=1.0). e,d pre-scaled by 32; S descaled by
// 1/1024 in the epilogue. R9 proved numerics (absmax 0.0); R10 fixes the R9
// scratch-spill (per-wave acc 128 -> 64 floats so VGPRs fit without AGPR help).

#define BDIM 4096
#define HDIM 2048
#define BM 128
#define BN 256
#define BK 128
#define NT (HDIM / BK)               // 16 K-tiles
#define NBLK ((BDIM/BM) * (BDIM/BN)) // 512 blocks

typedef __attribute__((ext_vector_type(4))) int   i32x4;
typedef __attribute__((ext_vector_type(8))) int   i32x8;
typedef __attribute__((ext_vector_type(4))) float f32x4;

__device__ __forceinline__ void gll16(const void* g, void* l) {
    __builtin_amdgcn_global_load_lds(
        (const __attribute__((address_space(1))) unsigned int*)g,
        (__attribute__((address_space(3))) unsigned int*)l,
        16, 0, 0);
}

__device__ __forceinline__ i32x8 mk8(i32x4 lo, i32x4 hi) {
    i32x8 r;
    r[0] = lo[0]; r[1] = lo[1]; r[2] = lo[2]; r[3] = lo[3];
    r[4] = hi[0]; r[5] = hi[1]; r[6] = hi[2]; r[7] = hi[3];
    return r;
}

// ---------------- Kernel 1: D-reduce + scale + cast to fp8 e4m3 ----------------
__global__ void reduce_cast(const float4* __restrict__ enc,
                            const float4* __restrict__ dec,
                            uint2* __restrict__ eb8,
                            uint2* __restrict__ db8) {
    int idx = blockIdx.x * blockDim.x + threadIdx.x;   // 0..1048575
    int b  = idx >> 8;
    int ch = idx & 255;
    int f4 = b * 1024 + ch * 2;

    {
        float4 a0 = enc[f4],       a1 = enc[f4 + 1];
        float4 c0 = enc[f4 + 512], c1 = enc[f4 + 512 + 1];
        int w0 = __builtin_amdgcn_cvt_pk_fp8_f32((a0.x + c0.x) * 32.f, (a0.y + c0.y) * 32.f, 0, false);
        w0     = __builtin_amdgcn_cvt_pk_fp8_f32((a0.z + c0.z) * 32.f, (a0.w + c0.w) * 32.f, w0, true);
        int w1 = __builtin_amdgcn_cvt_pk_fp8_f32((a1.x + c1.x) * 32.f, (a1.y + c1.y) * 32.f, 0, false);
        w1     = __builtin_amdgcn_cvt_pk_fp8_f32((a1.z + c1.z) * 32.f, (a1.w + c1.w) * 32.f, w1, true);
        eb8[idx] = make_uint2((unsigned int)w0, (unsigned int)w1);
    }
    {
        float4 a0 = dec[f4],       a1 = dec[f4 + 1];
        float4 c0 = dec[f4 + 512], c1 = dec[f4 + 512 + 1];
        int w0 = __builtin_amdgcn_cvt_pk_fp8_f32((a0.x + c0.x) * 32.f, (a0.y + c0.y) * 32.f, 0, false);
        w0     = __builtin_amdgcn_cvt_pk_fp8_f32((a0.z + c0.z) * 32.f, (a0.w + c0.w) * 32.f, w0, true);
        int w1 = __builtin_amdgcn_cvt_pk_fp8_f32((a1.x + c1.x) * 32.f, (a1.y + c1.y) * 32.f, 0, false);
        w1     = __builtin_amdgcn_cvt_pk_fp8_f32((a1.z + c1.z) * 32.f, (a1.w + c1.w) * 32.f, w1, true);
        db8[idx] = make_uint2((unsigned int)w0, (unsigned int)w1);
    }
}

// ------------- Kernel 2: MX-fp8 128x256 GEMM (K-tile 128) + fused log-sigmoid -------------
// 8 waves (2M x 4N), per-wave 64x64 output, acc[4][4] f32x4 (64 f32 — spill-free),
// mfma_scale 16x16x128 fp8 (scales = 1.0). LDS 96 KiB: 2 bufs x (A[128][128] + B[256][128]).
// Fence-light loop (R8-proven): per tile {6 gll stage(t+1 -> buf^1); 16 ds_read_b128 +
// 16 MFMA unfenced; lgkmcnt(0)+vmcnt(0); s_barrier}. Slot-XOR swizzle ^(row&7) on read,
// source col inverse-XOR'd (cancels to linear k-map; R9-verified absmax 0.0).
__global__ __launch_bounds__(512, 2) void gemm_reduce(
        const unsigned char* __restrict__ eb,
        const unsigned char* __restrict__ db,
        float* __restrict__ pall,
        float* __restrict__ pdiag) {
    __shared__ __align__(16) unsigned char lds8[98304];  // buf*49152: A 0..32767(16K), B 32768..49151

    const int tid  = threadIdx.x;
    const int lane = tid & 63;
    const int wid  = tid >> 6;          // 0..7
    const int wr   = wid >> 2;          // 0..1  (M)
    const int wc   = wid & 3;           // 0..3  (N)
    const int bm   = blockIdx.y, bn = blockIdx.x;
    const int row0 = bm * BM, col0 = bn * BN;

    const int fr = lane & 15;           // fragment row/col
    const int kg = lane >> 4;           // 32B k-granule (0..3) within K=128
    const int s0 = (2 * kg)     ^ (fr & 7);   // swizzled 16B slot, low half
    const int s1 = (2 * kg + 1) ^ (fr & 7);   // swizzled 16B slot, high half

    // staging: thread t covers (row = c*64 + t>>3, slot = t&7) of a 64-row chunk;
    // source col inverse-XOR'd so linear LDS dest + XOR read = identity.
    const int su = tid >> 3;                              // 0..63
    const int sx = ((tid & 7) ^ (su & 7)) << 4;           // source byte offset in row

    f32x4 acc[4][4] = {};

#define ST_A(tp) { const int kt = (tp) * BK; unsigned char* d = &lds8[((tp) & 1) * 49152]; \
    _Pragma("unroll") for (int c = 0; c < 2; ++c) \
        gll16(eb + (size_t)(row0 + c * 64 + su) * HDIM + kt + sx, d + c * 8192 + tid * 16); }
#define ST_B(tp) { const int kt = (tp) * BK; unsigned char* d = &lds8[((tp) & 1) * 49152 + 16384]; \
    _Pragma("unroll") for (int c = 0; c < 4; ++c) \
        gll16(db + (size_t)(col0 + c * 64 + su) * HDIM + kt + sx, d + c * 8192 + tid * 16); }

#define RD16(base, r, sl) (*(const i32x4*)&lds8[(base) + (r) * 128 + ((sl) << 4)])

    // one K-tile (K=128): stage next, read 4 B-frags + 4 A-frags, 16 MFMA, gate+barrier
#define TILE(tau, buf) {                                                         \
    if ((tau) + 1 < NT) { ST_A((tau) + 1) ST_B((tau) + 1) }                      \
    const int ab = (buf) * 49152, bb = ab + 16384;                               \
    i32x8 bfr[4];                                                                \
    _Pragma("unroll") for (int n = 0; n < 4; ++n) {                              \
        const int rB = wc * 64 + n * 16 + fr;                                    \
        bfr[n] = mk8(RD16(bb, rB, s0), RD16(bb, rB, s1));                        \
    }                                                                            \
    _Pragma("unroll") for (int m = 0; m < 4; ++m) {                              \
        const int rA = wr * 64 + m * 16 + fr;                                    \
        i32x8 af = mk8(RD16(ab, rA, s0), RD16(ab, rA, s1));                      \
        _Pragma("unroll") for (int n = 0; n < 4; ++n)                            \
            acc[m][n] = __builtin_amdgcn_mfma_scale_f32_16x16x128_f8f6f4(        \
                af, bfr[n], acc[m][n], 0, 0,                                     \
                0, 0x7F7F7F7F, 0, 0x7F7F7F7F);                                   \
    }                                                                            \
    asm volatile("s_waitcnt lgkmcnt(0) vmcnt(0)" ::: "memory");                  \
    __builtin_amdgcn_s_barrier(); }

    // prologue: tile 0 -> buf0
    ST_A(0) ST_B(0)
    asm volatile("s_waitcnt vmcnt(0)" ::: "memory");
    __builtin_amdgcn_s_barrier();

    for (int tt = 0; tt < NT; tt += 2) {
        TILE(tt, 0)
        TILE(tt + 1, 1)
    }
#undef TILE
#undef RD16
#undef ST_A
#undef ST_B

    // ---- epilogue: descale + log-sigmoid + reduce ----
    // C/D layout: col = lane&15, row = (lane>>4)*4 + reg (shape-determined, m128)
    const int rbase = row0 + wr * 64 + (kg * 4);
    const int cbase = col0 + wc * 64 + fr;
    float s_all = 0.f, s_diag = 0.f;
#pragma unroll
    for (int m = 0; m < 4; ++m) {
#pragma unroll
        for (int n = 0; n < 4; ++n) {
#pragma unroll
            for (int r = 0; r < 4; ++r) {
                float xs = acc[m][n][r] * 0.0009765625f;   // /1024 descale (32*32)
                int row = rbase + m * 16 + r;
                int col = cbase + n * 16;
                bool dg = (row == col);
                float x = dg ? xs : -xs;
                float ll = fminf(x, 0.f) - __logf(1.f + __expf(-fabsf(x)));
                s_all += ll;
                if (dg) s_diag += ll;
            }
        }
    }

#pragma unroll
    for (int off = 32; off; off >>= 1) {
        s_all  += __shfl_down(s_all, off);
        s_diag += __shfl_down(s_diag, off);
    }
    __syncthreads();                    // resync before LDS reuse
    float* red = (float*)lds8;
    if (lane == 0) { red[wid] = s_all; red[8 + wid] = s_diag; }
    __syncthreads();
    if (tid == 0) {
        float A = 0.f, D = 0.f;
#pragma unroll
        for (int w = 0; w < 8; ++w) { A += red[w]; D += red[8 + w]; }
        int bflat = bm * gridDim.x + bn;
        pall[bflat]  = A;
        pdiag[bflat] = D;
    }
}

// ---------------- Kernel 3: finalize ----------------
__global__ void finalize(const float* __restrict__ pall,
                         const float* __restrict__ pdiag,
                         float* __restrict__ out) {
    float a = 0.f, d = 0.f;
    for (int i = threadIdx.x; i < NBLK; i += 256) { a += pall[i]; d += pdiag[i]; }
#pragma unroll
    for (int off = 32; off; off >>= 1) {
        a += __shfl_down(a, off);
        d += __shfl_down(d, off);
    }
    __shared__ float r[8];
    int wid = threadIdx.x >> 6, lane = threadIdx.x & 63;
    if (lane == 0) { r[wid] = a; r[4 + wid] = d; }
    __syncthreads();
    if (threadIdx.x == 0) {
        float A = r[0] + r[1] + r[2] + r[3];
        float D = r[4] + r[5] + r[6] + r[7];
        out[0] = -(A + 39.f * D) / (float)BDIM;  // logLoss
        out[1] = -(40.f * D) / (float)BDIM;      // diagonalLoss
    }
}

extern "C" void kernel_launch(void* const* d_in, const int* in_sizes, int n_in,
                              void* d_out, int out_size, void* d_ws, size_t ws_size,
                              hipStream_t stream) {
    const float* enc = (const float*)d_in[0];
    const float* dec = (const float*)d_in[1];
    float* out = (float*)d_out;

    char* ws = (char*)d_ws;
    // ws: eb 8MB | db 8MB | pall 2KB | pdiag 2KB
    unsigned char* eb = (unsigned char*)ws;
    unsigned char* db = (unsigned char*)(ws + (size_t)8 * 1024 * 1024);
    float* pall  = (float*)(ws + (size_t)16 * 1024 * 1024);
    float* pdiag = pall + NBLK;

    reduce_cast<<<4096, 256, 0, stream>>>(
        (const float4*)enc, (const float4*)dec, (uint2*)eb, (uint2*)db);

    dim3 grid(BDIM / BN, BDIM / BM);  // (16, 32) = 512 blocks
    gemm_reduce<<<grid, 512, 0, stream>>>(eb, db, pall, pdiag);

    finalize<<<1, 256, 0, stream>>>(pall, pdiag, out);
}